// Round 16
// baseline (119.577 us; speedup 1.0000x reference)
//
#include <hip/hip_runtime.h>
#include <hip/hip_bf16.h>
#include <math.h>

#define B_ 2
#define T_ 512
#define D_ 1024
#define H_ 16
#define R_ 32
#define DH 64
#define BT_ (B_*T_)
#define BH_ (B_*H_)

typedef __attribute__((ext_vector_type(8))) short bf16x8;
typedef __attribute__((ext_vector_type(4))) short s16x4;
typedef __attribute__((ext_vector_type(4))) float f32x4;

#define MFMA_BF16(a, b, c) __builtin_amdgcn_mfma_f32_16x16x32_bf16(a, b, c, 0, 0, 0)

static __device__ __forceinline__ short bf16s(float v) {
  __hip_bfloat16 b = __float2bfloat16(v);
  return *reinterpret_cast<short*>(&b);
}
static __device__ __forceinline__ float b2f(__hip_bfloat16 h) { return __bfloat162float(h); }

// attn task table: 15 tasks/bh; rows 0-2 single, rows 3-5 2-way, rows 6-7 3-way (max 3 tiles)
__constant__ int ATT_IT[15]   = {0,1,2, 3,3, 4,4, 5,5, 6,6,6, 7,7,7};
__constant__ int ATT_J0[15]   = {0,0,0, 0,2, 0,3, 0,3, 0,3,5, 0,3,6};
__constant__ int ATT_J1[15]   = {0,1,2, 1,3, 2,4, 2,5, 2,4,6, 2,5,7};
__constant__ int ATT_SLOT[15] = {-1,-1,-1, 0,0, 1,1, 2,2, 3,3,3, 4,4,4};
__constant__ int ATT_PART[15] = {-1,-1,-1, 0,1, 0,1, 0,1, 0,1,2, 0,1,2};
__constant__ int MRG_NP[5]    = {2,2,2,3,3};   // parts per slot (slot s -> row s+3)

// ---- padded-tile helpers ([72] pad = 144B stride, conflict-free) ----
__device__ __forceinline__ bf16x8 ldfrag(const __hip_bfloat16 s[][72], int b16, int kb, int fr, int kq) {
  return *(const bf16x8*)&s[b16 * 16 + fr][kb * 32 + kq * 8];
}
__device__ __forceinline__ void stage64(const __hip_bfloat16* __restrict__ g, int ldg,
                                        __hip_bfloat16 s[][72], int tid) {
#pragma unroll
  for (int l = 0; l < 2; ++l) {
    int f = tid + l * 256;
    int r = f >> 3, c = (f & 7) << 3;
    *(int4*)&s[r][c] = *(const int4*)&g[(size_t)r * ldg + c];
  }
}

// ---- global_load_lds 16B direct-to-LDS (GEMMs only; linear dest per rule #21) ----
typedef const __attribute__((address_space(1))) void* as1cv;
typedef __attribute__((address_space(3))) void* as3v;
__device__ __forceinline__ void gl16(const __hip_bfloat16* g, __hip_bfloat16* l) {
  __builtin_amdgcn_global_load_lds((as1cv)g, (as3v)l, 16, 0, 0);
}
__device__ __forceinline__ void stage64s(const __hip_bfloat16* __restrict__ g, int ldg,
                                         __hip_bfloat16* s, int tid) {
#pragma unroll
  for (int i = 0; i < 2; ++i) {
    int chunk = tid + i * 256;
    int r = chunk >> 3, c8 = (chunk & 7) ^ (r & 7);
    gl16(g + (size_t)r * ldg + c8 * 8, s + chunk * 8);
  }
}
__device__ __forceinline__ bf16x8 ldfragS(const __hip_bfloat16* s, int b16, int half, int fr, int kq) {
  int r = b16 * 16 + fr;
  int col8 = ((kq + half * 4) ^ (r & 7)) * 8;
  return *(const bf16x8*)&s[r * 64 + col8];
}

// ======================= prep: split x (hi/lo), transpose weights (hi), splitcat ==========
__global__ __launch_bounds__(256) void prep_k(const float* __restrict__ x,
                                              const float* __restrict__ Wq,
                                              const float* __restrict__ Wk,
                                              const float* __restrict__ Wv,
                                              const float* __restrict__ Wo,
                                              const float* __restrict__ wA,
                                              const float* __restrict__ bw,
                                              const float* __restrict__ gw,
                                              __hip_bfloat16* __restrict__ xhi,
                                              __hip_bfloat16* __restrict__ xlo,
                                              __hip_bfloat16* __restrict__ wqkvT,  // [3072][D]
                                              __hip_bfloat16* __restrict__ woT,    // [1024][D]
                                              __hip_bfloat16* __restrict__ wcThi,
                                              __hip_bfloat16* __restrict__ wcTlo) {
  __shared__ float tile[64][65];
  const int bid = blockIdx.x, tid = threadIdx.x;
  if (bid < 512) {
    int i8 = bid * 256 + tid;
    float4 v0 = ((const float4*)x)[i8 * 2];
    float4 v1 = ((const float4*)x)[i8 * 2 + 1];
    float c[8] = {v0.x, v0.y, v0.z, v0.w, v1.x, v1.y, v1.z, v1.w};
    bf16x8 ph, pl;
#pragma unroll
    for (int u = 0; u < 8; ++u) {
      __hip_bfloat16 h = __float2bfloat16(c[u]);
      ph[u] = *reinterpret_cast<short*>(&h);
      pl[u] = bf16s(c[u] - __bfloat162float(h));
    }
    *(bf16x8*)&xhi[(size_t)i8 * 8] = ph;
    *(bf16x8*)&xlo[(size_t)i8 * 8] = pl;
  } else if (bid < 1536) {
    const int zz = (bid - 512) >> 8, idx = (bid - 512) & 255;
    const float* Wm = (zz == 0) ? Wq : (zz == 1) ? Wk : (zz == 2) ? Wv : Wo;
    __hip_bfloat16* thi = (zz < 3) ? (wqkvT + (size_t)zz * 1024 * D_) : woT;
    const int bn = (idx & 15) * 64, bk = (idx >> 4) * 64;
#pragma unroll
    for (int l = 0; l < 4; ++l) {
      int f = tid + l * 256; int r = f >> 4, c = (f & 15) << 2;
      *(float4*)&tile[r][c] = *(const float4*)&Wm[(size_t)(bk + r) * D_ + bn + c];
    }
    __syncthreads();
#pragma unroll
    for (int l = 0; l < 4; ++l) {
      int f = tid + l * 256; int n = f >> 4, k0 = (f & 15) << 2;
      s16x4 ph;
#pragma unroll
      for (int u = 0; u < 4; ++u) ph[u] = bf16s(tile[k0 + u][n]);
      *(s16x4*)&thi[(size_t)(bn + n) * D_ + bk + k0] = ph;
    }
  } else {
    int n = bid - 1536;
    for (int k = tid; k < D_; k += 256) {
      float v;
      if (n < 32) v = wA[(size_t)k * R_ + n];
      else if (n < 48) v = bw[(size_t)k * H_ + (n - 32)];
      else v = gw[(size_t)k * H_ + (n - 48)];
      __hip_bfloat16 h = __float2bfloat16(v);
      wcThi[(size_t)n * D_ + k] = h;
      wcTlo[(size_t)n * D_ + k] = __float2bfloat16(v - __bfloat162float(h));
    }
  }
}

// ======================= merged QKV projection + ycat partials =======================
__global__ __launch_bounds__(256) void gemm_qkv_ycat(const __hip_bfloat16* __restrict__ ah,
                                                     const __hip_bfloat16* __restrict__ al,
                                                     const __hip_bfloat16* __restrict__ bT,
                                                     const __hip_bfloat16* __restrict__ wch,
                                                     const __hip_bfloat16* __restrict__ wcl,
                                                     __hip_bfloat16* __restrict__ qb,
                                                     __hip_bfloat16* __restrict__ kb,
                                                     __hip_bfloat16* __restrict__ vhi,
                                                     float* __restrict__ ypart,
                                                     const float* __restrict__ qnw,
                                                     const float* __restrict__ knw) {
  __shared__ __align__(16) char smem[43008];   // 42 KB union
  const int bx = blockIdx.x, bm = blockIdx.y * 64;
  const int tid = threadIdx.x, w = tid >> 6, lane = tid & 63;
  const int fr = lane & 15, kq = lane >> 4;
  const f32x4 zf = {0.f, 0.f, 0.f, 0.f};
  f32x4 acc[4] = {zf, zf, zf, zf};

  if (bx < 48) {
    __hip_bfloat16* As = (__hip_bfloat16*)smem;              // [2][64][64]
    __hip_bfloat16* Bs = As + 2 * 4096;                      // [2][64][64]
    __hip_bfloat16 (*Lt)[72] = (__hip_bfloat16(*)[72])(Bs + 2 * 4096);  // [64][72]
    const int bn = bx * 64;
    const __hip_bfloat16* ap = ah + (size_t)bm * D_;
    const __hip_bfloat16* bp = bT + (size_t)bn * D_;
    stage64s(ap, D_, As, tid);
    stage64s(bp, D_, Bs, tid);
    __syncthreads();
    for (int t = 0; t < 16; ++t) {
      const int cur = t & 1;
      if (t < 15) {
        stage64s(ap + (t + 1) * 64, D_, As + (cur ^ 1) * 4096, tid);
        stage64s(bp + (t + 1) * 64, D_, Bs + (cur ^ 1) * 4096, tid);
      }
      bf16x8 a0 = ldfragS(As + cur * 4096, w, 0, fr, kq);
      bf16x8 a1 = ldfragS(As + cur * 4096, w, 1, fr, kq);
#pragma unroll
      for (int n = 0; n < 4; ++n) {
        acc[n] = MFMA_BF16(a0, ldfragS(Bs + cur * 4096, n, 0, fr, kq), acc[n]);
        acc[n] = MFMA_BF16(a1, ldfragS(Bs + cur * 4096, n, 1, fr, kq), acc[n]);
      }
      __syncthreads();
    }
    if (bn < 2048) {
      float rs[4];
#pragma unroll
      for (int reg = 0; reg < 4; ++reg) {
        float s = 0.f;
#pragma unroll
        for (int n = 0; n < 4; ++n) s += acc[n][reg] * acc[n][reg];
#pragma unroll
        for (int mm = 1; mm <= 8; mm <<= 1) s += __shfl_xor(s, mm);
        rs[reg] = rsqrtf(s * (1.f / DH) + 1e-5f);
      }
      const bool isq = (bn < 1024);
      __hip_bfloat16* outp = isq ? qb : kb;
#pragma unroll
      for (int n = 0; n < 4; ++n) {
        int gn = bn + n * 16 + fr;
        int dd = gn & 63, h = (gn & 1023) >> 6;
        float nw = (isq ? qnw : knw)[dd];
#pragma unroll
        for (int reg = 0; reg < 4; ++reg) {
          int gm = bm + w * 16 + kq * 4 + reg;
          int bb = gm >> 9, tt = gm & 511;
          outp[(((size_t)(bb * H_ + h)) * T_ + tt) * DH + dd] =
              __float2bfloat16(acc[n][reg] * rs[reg] * nw);
        }
      }
    } else {
      const int row0 = w * 16 + kq * 4;
#pragma unroll
      for (int n = 0; n < 4; ++n) {
        int dd = n * 16 + fr;
#pragma unroll
        for (int reg = 0; reg < 4; ++reg) Lt[dd][row0 + reg] = __float2bfloat16(acc[n][reg]);
      }
      __syncthreads();
      const int b = bm >> 9, t0 = bm & 511, h = (bn - 2048) >> 6;
      const size_t base = ((size_t)(b * H_ + h)) * DH * T_;
#pragma unroll
      for (int l = 0; l < 2; ++l) {
        int f = tid + l * 256;
        int dd = f >> 3, tq = (f & 7) * 8;
        *(bf16x8*)&vhi[base + (size_t)dd * T_ + t0 + tq] = *(const bf16x8*)&Lt[dd][tq];
      }
    }
  } else {
    __hip_bfloat16 (*Ah)[72] = (__hip_bfloat16(*)[72])smem;
    __hip_bfloat16 (*Al)[72] = (__hip_bfloat16(*)[72])(smem + 9216);
    __hip_bfloat16 (*Bh)[72] = (__hip_bfloat16(*)[72])(smem + 18432);
    __hip_bfloat16 (*Bl)[72] = (__hip_bfloat16(*)[72])(smem + 27648);
    const int z = bx - 48;
    float* C = ypart + (size_t)z * (BT_ * 64);
    for (int k0 = z * 256; k0 < z * 256 + 256; k0 += 64) {
      __syncthreads();
      stage64(ah + (size_t)bm * D_ + k0, D_, Ah, tid);
      stage64(al + (size_t)bm * D_ + k0, D_, Al, tid);
      stage64(wch + k0, D_, Bh, tid);
      stage64(wcl + k0, D_, Bl, tid);
      __syncthreads();
      bf16x8 ah0 = ldfrag(Ah, w, 0, fr, kq), ah1 = ldfrag(Ah, w, 1, fr, kq);
      bf16x8 al0 = ldfrag(Al, w, 0, fr, kq), al1 = ldfrag(Al, w, 1, fr, kq);
#pragma unroll
      for (int nb = 0; nb < 4; ++nb) {
        bf16x8 b0 = ldfrag(Bh, nb, 0, fr, kq), b1 = ldfrag(Bh, nb, 1, fr, kq);
        bf16x8 c0 = ldfrag(Bl, nb, 0, fr, kq), c1 = ldfrag(Bl, nb, 1, fr, kq);
        acc[nb] = MFMA_BF16(ah0, b0, acc[nb]); acc[nb] = MFMA_BF16(ah1, b1, acc[nb]);
        acc[nb] = MFMA_BF16(ah0, c0, acc[nb]); acc[nb] = MFMA_BF16(ah1, c1, acc[nb]);
        acc[nb] = MFMA_BF16(al0, b0, acc[nb]); acc[nb] = MFMA_BF16(al1, b1, acc[nb]);
      }
    }
#pragma unroll
    for (int nb = 0; nb < 4; ++nb) {
      int n = nb * 16 + fr;
#pragma unroll
      for (int reg = 0; reg < 4; ++reg) {
        int m = bm + w * 16 + kq * 4 + reg;
        C[(size_t)m * 64 + n] = acc[nb][reg];
      }
    }
  }
}

// ======================= Wo projection: dbuf 1-pass bf16 -> fp32 =======================
__global__ __launch_bounds__(256) void gemm_o(const __hip_bfloat16* __restrict__ ah,
                                              const __hip_bfloat16* __restrict__ bT,
                                              float* __restrict__ C) {
  __shared__ __hip_bfloat16 As[2][64][64];
  __shared__ __hip_bfloat16 Bs[2][64][64];
  const int bm = blockIdx.y * 64, bn = blockIdx.x * 64;
  const int tid = threadIdx.x, w = tid >> 6, lane = tid & 63;
  const int fr = lane & 15, kq = lane >> 4;
  const f32x4 zf = {0.f, 0.f, 0.f, 0.f};
  f32x4 acc[4] = {zf, zf, zf, zf};
  const __hip_bfloat16* ap = ah + (size_t)bm * D_;
  const __hip_bfloat16* bp = bT + (size_t)bn * D_;
  stage64s(ap, D_, &As[0][0][0], tid);
  stage64s(bp, D_, &Bs[0][0][0], tid);
  __syncthreads();
  for (int t = 0; t < 16; ++t) {
    const int cur = t & 1;
    if (t < 15) {
      stage64s(ap + (t + 1) * 64, D_, &As[cur ^ 1][0][0], tid);
      stage64s(bp + (t + 1) * 64, D_, &Bs[cur ^ 1][0][0], tid);
    }
    bf16x8 a0 = ldfragS(&As[cur][0][0], w, 0, fr, kq);
    bf16x8 a1 = ldfragS(&As[cur][0][0], w, 1, fr, kq);
#pragma unroll
    for (int n = 0; n < 4; ++n) {
      acc[n] = MFMA_BF16(a0, ldfragS(&Bs[cur][0][0], n, 0, fr, kq), acc[n]);
      acc[n] = MFMA_BF16(a1, ldfragS(&Bs[cur][0][0], n, 1, fr, kq), acc[n]);
    }
    __syncthreads();
  }
#pragma unroll
  for (int n = 0; n < 4; ++n) {
    int gn = bn + n * 16 + fr;
#pragma unroll
    for (int reg = 0; reg < 4; ++reg) {
      int gm = bm + w * 16 + kq * 4 + reg;
      C[(size_t)gm * D_ + gn] = acc[n][reg];
    }
  }
}

// ======================= merged gates + wdir (both read ypart) =======================
__global__ __launch_bounds__(512) void gate_wdir(const float* __restrict__ ypart,
                                                 const float* __restrict__ gb,
                                                 const float* __restrict__ wB,
                                                 const float* __restrict__ convw,
                                                 float* __restrict__ beta,
                                                 float* __restrict__ G,
                                                 float* __restrict__ wT,
                                                 __hip_bfloat16* __restrict__ wb16) {
  __shared__ float shm[T_];
  const int bid = blockIdx.x, tid = threadIdx.x;
  if (bid < BT_) {
    int bt = bid, b = bt / T_, t = bt - b * T_;
    float* wl = shm;                      // [3][32]
    if (tid < 3 * R_) {
      int row = tid / R_, r = tid - row * R_;
      int ts = t - row;
      float a = 0.f;
      if (ts >= 0) {
#pragma unroll
        for (int z = 0; z < 4; ++z)
          a += ypart[(size_t)z * (BT_ * 64) + (size_t)(b * T_ + ts) * 64 + r];
      }
      wl[row * R_ + r] = a;
    }
    __syncthreads();
#pragma unroll
    for (int half = 0; half < 2; ++half) {
      int col = tid + half * 512;
      float f0 = 0.f, f1 = 0.f, f2 = 0.f;
      for (int r = 0; r < R_; ++r) {
        float wb = wB[(size_t)r * D_ + col];
        f0 += wl[0 * R_ + r] * wb; f1 += wl[1 * R_ + r] * wb; f2 += wl[2 * R_ + r] * wb;
      }
      float y = f2 * convw[col * 3 + 0] + f1 * convw[col * 3 + 1] + f0 * convw[col * 3 + 2];
      float s = y / (1.f + expf(-y));
      float ss = s * s;
#pragma unroll
      for (int m = 32; m >= 1; m >>= 1) ss += __shfl_xor(ss, m);
      float outv = s * rsqrtf(ss + 1e-12f);
      int h = col >> 6, dd = col & 63;
      size_t o = (((size_t)(b * H_ + h)) * T_ + t) * DH + dd;
      wT[o] = outv;
      wb16[o] = __float2bfloat16(outv);
    }
  } else {
    int bh = bid - BT_, b = bh >> 4, h = bh & 15, t = tid;
    int bt = b * T_ + t;
    float by = 0.f, gy = gb[h];
#pragma unroll
    for (int z = 0; z < 4; ++z) {
      const float* yp = ypart + (size_t)z * (BT_ * 64) + (size_t)bt * 64;
      by += yp[32 + h];
      gy += yp[48 + h];
    }
    beta[(size_t)bh * T_ + t] = 2.f / (1.f + expf(-by));
    shm[t] = fminf(gy, 0.f) - log1pf(expf(-fabsf(gy)));
    __syncthreads();
    for (int off = 1; off < T_; off <<= 1) {
      float v = (t >= off) ? shm[t - off] : 0.f;
      __syncthreads();
      shm[t] += v;
      __syncthreads();
    }
    G[(size_t)bh * T_ + t] = shm[t];
  }
}

// ======================= unit-lower inverse, 8-row blocked substitution =======================
__global__ __launch_bounds__(256) void linv_k(const float* __restrict__ wT,
                                              const float* __restrict__ beta,
                                              __hip_bfloat16* __restrict__ linv) {
  __shared__ float Wsh[64][68];
  __shared__ float Csh[64][65];
  __shared__ float Li[64][68];
  __shared__ float bI[64];
  const int I = blockIdx.x, bhx = blockIdx.y;
  const int tid = threadIdx.x;
#pragma unroll
  for (int l = 0; l < 4; ++l) {
    int f = tid + l * 256; int r = f >> 4, c = (f & 15) << 2;
    *(float4*)&Wsh[r][c] = *(const float4*)&wT[((size_t)bhx * T_ + I * 64 + r) * DH + c];
  }
  if (tid < 64) bI[tid] = beta[(size_t)bhx * T_ + I * 64 + tid];
#pragma unroll
  for (int l = 0; l < 16; ++l) {
    int e = tid + l * 256; int r = e >> 6, c = e & 63;
    Li[r][c] = (r == c) ? 1.f : 0.f;
  }
  __syncthreads();
  const int tm = (tid >> 4) << 2, tn = (tid & 15) << 2;
  float cc[4][4] = {};
  for (int dd = 0; dd < 64; ++dd) {
    float a0 = Wsh[tm + 0][dd], a1 = Wsh[tm + 1][dd], a2 = Wsh[tm + 2][dd], a3 = Wsh[tm + 3][dd];
    float b0 = Wsh[tn + 0][dd], b1 = Wsh[tn + 1][dd], b2 = Wsh[tn + 2][dd], b3 = Wsh[tn + 3][dd];
    cc[0][0] += a0 * b0; cc[0][1] += a0 * b1; cc[0][2] += a0 * b2; cc[0][3] += a0 * b3;
    cc[1][0] += a1 * b0; cc[1][1] += a1 * b1; cc[1][2] += a1 * b2; cc[1][3] += a1 * b3;
    cc[2][0] += a2 * b0; cc[2][1] += a2 * b1; cc[2][2] += a2 * b2; cc[2][3] += a2 * b3;
    cc[3][0] += a3 * b0; cc[3][1] += a3 * b1; cc[3][2] += a3 * b2; cc[3][3] += a3 * b3;
  }
#pragma unroll
  for (int ii = 0; ii < 4; ++ii)
#pragma unroll
    for (int jj = 0; jj < 4; ++jj)
      Csh[tm + ii][tn + jj] = (tm + ii > tn + jj) ? cc[ii][jj] * bI[tn + jj] : 0.f;
  __syncthreads();
  const int sL = tid & 63, g = tid >> 6;
  for (int r0 = 0; r0 < 64; r0 += 8) {
    float a[8];
#pragma unroll
    for (int u = 0; u < 8; ++u) a[u] = Li[r0 + u][sL];
    __syncthreads();
#pragma unroll
    for (int u = 1; u < 8; ++u)
#pragma unroll
      for (int s = 0; s < u; ++s) a[u] -= Csh[r0 + u][r0 + s] * a[s];
    if (g == 0) {
#pragma unroll
      for (int u = 1; u < 8; ++u) Li[r0 + u][sL] = a[u];
    }
    for (int r2 = r0 + 8 + g; r2 < 64; r2 += 4) {
      float acc = Li[r2][sL];
#pragma unroll
      for (int u = 0; u < 8; ++u) acc -= Csh[r2][r0 + u] * a[u];
      Li[r2][sL] = acc;
    }
    __syncthreads();
  }
#pragma unroll
  for (int l = 0; l < 4; ++l) {
    int f = tid + l * 256; int r = f >> 4, c0 = (f & 15) << 2;
    s16x4 p;
    p.x = bf16s(Li[r][c0 + 0]); p.y = bf16s(Li[r][c0 + 1]);
    p.z = bf16s(Li[r][c0 + 2]); p.w = bf16s(Li[r][c0 + 3]);
    *(s16x4*)&linv[((size_t)(bhx * 8 + I)) * 4096 + r * 64 + c0] = p;
  }
}

// ======================= WY chain, khat-first, 3 barriers/iter =======================
// Barrier audit: B4(prev iter) covers all prev readers of Ws/Ls/Kh/bI before this
// iter's writes; pre-loop barrier covers Kb staging. B2: stages+Kh visible. B3: Ps/WsT.
__global__ __launch_bounds__(256) void chain_k(const __hip_bfloat16* __restrict__ kb,
                                               const __hip_bfloat16* __restrict__ wb,
                                               const __hip_bfloat16* __restrict__ linv,
                                               const float* __restrict__ beta,
                                               __hip_bfloat16* __restrict__ abT,
                                               __hip_bfloat16* __restrict__ khat) {
  __shared__ __hip_bfloat16 Kb[64][72];
  __shared__ __hip_bfloat16 Ws[64][72];
  __shared__ __hip_bfloat16 WsT[64][72];
  __shared__ __hip_bfloat16 Ls[64][72];
  __shared__ __hip_bfloat16 Kh[64][72];
  __shared__ __hip_bfloat16 Ps[64][72];
  __shared__ __hip_bfloat16 Xs[64][72];
  __shared__ float bI[64];
  const int ch = blockIdx.x, bhx = blockIdx.y;
  const int tid = threadIdx.x, w = tid >> 6, lane = tid & 63;
  const int fr = lane & 15, kq = lane >> 4;
  const int jr = w * 16 + kq * 4;
  const size_t hb = (size_t)bhx * T_;
  const f32x4 zf = {0.f, 0.f, 0.f, 0.f};

  stage64(kb + (hb + ch * 64) * DH, DH, Kb, tid);
  f32x4 macc[4] = {zf, zf, zf, zf};
  __syncthreads();                                            // Kb visible

  for (int I = ch; I < 8; ++I) {
    stage64(wb + (hb + I * 64) * DH, DH, Ws, tid);
    stage64(linv + ((size_t)(bhx * 8 + I)) * 4096, 64, Ls, tid);
    if (tid < 64) bI[tid] = beta[hb + I * 64 + tid];
#pragma unroll
    for (int nb = 0; nb < 4; ++nb) {
      int d = nb * 16 + fr;
#pragma unroll
      for (int reg = 0; reg < 4; ++reg)
        Kh[jr + reg][d] = __float2bfloat16(b2f(Kb[jr + reg][d]) - macc[nb][reg]);
    }
    __syncthreads();                                           // B2: stages + Kh visible
#pragma unroll
    for (int l = 0; l < 2; ++l) {
      int f = tid + l * 256;
      int r = f >> 3, c = (f & 7) << 3;
      *(int4*)&khat[(((size_t)(bhx * 8 + I)) * T_ + ch * 64 + r) * DH + c] = *(const int4*)&Kh[r][c];
    }
#pragma unroll
    for (int l = 0; l < 16; ++l) {
      int e = tid + l * 256;
      int t = e >> 6, d = e & 63;
      WsT[d][t] = Ws[t][d];
    }
    bf16x8 kh0 = ldfrag(Kh, w, 0, fr, kq), kh1 = ldfrag(Kh, w, 1, fr, kq);
    f32x4 pt[4];
#pragma unroll
    for (int nb = 0; nb < 4; ++nb) {
      pt[nb] = MFMA_BF16(kh0, ldfrag(Ws, nb, 0, fr, kq), zf);
      pt[nb] = MFMA_BF16(kh1, ldfrag(Ws, nb, 1, fr, kq), pt[nb]);
    }
#pragma unroll
    for (int nb = 0; nb < 4; ++nb) {
      int t = nb * 16 + fr;
#pragma unroll
      for (int reg = 0; reg < 4; ++reg) {
        float v = pt[nb][reg];
        if (I == ch && t <= jr + reg) v = 0.f;
        Ps[jr + reg][t] = __float2bfloat16(v);
      }
    }
    __syncthreads();                                           // B3: Ps & WsT visible
    bf16x8 la0 = ldfrag(Ls, w, 0, fr, kq), la1 = ldfrag(Ls, w, 1, fr, kq);
    f32x4 av[4];
#pragma unroll
    for (int nb = 0; nb < 4; ++nb) {
      av[nb] = MFMA_BF16(la0, ldfrag(Ps, nb, 0, fr, kq), zf);
      av[nb] = MFMA_BF16(la1, ldfrag(Ps, nb, 1, fr, kq), av[nb]);
    }
#pragma unroll
    for (int nb = 0; nb < 4; ++nb) {
      s16x4 p;
      p.x = bf16s(bI[jr + 0] * av[nb][0]);
      p.y = bf16s(bI[jr + 1] * av[nb][1]);
      p.z = bf16s(bI[jr + 2] * av[nb][2]);
      p.w = bf16s(bI[jr + 3] * av[nb][3]);
      *(s16x4*)&Xs[nb * 16 + fr][jr] = p;
    }
    __syncthreads();                                           // B4: Xs visible; all Ws/Ls/Kh/bI readers done
#pragma unroll
    for (int l = 0; l < 2; ++l) {
      int f = tid + l * 256;
      int r = f >> 3, c = (f & 7) << 3;
      *(int4*)&abT[(hb + ch * 64 + r) * T_ + I * 64 + c] = *(const int4*)&Xs[r][c];
    }
    bf16x8 xa0 = ldfrag(Xs, w, 0, fr, kq), xa1 = ldfrag(Xs, w, 1, fr, kq);
#pragma unroll
    for (int nb = 0; nb < 4; ++nb) {
      macc[nb] = MFMA_BF16(xa0, ldfrag(WsT, nb, 0, fr, kq), macc[nb]);
      macc[nb] = MFMA_BF16(xa1, ldfrag(WsT, nb, 1, fr, kq), macc[nb]);
    }
  }
}

// ======================= fused attention, task-balanced (15 tasks/bh, max 3 tiles) =========
__global__ __launch_bounds__(256) void attn_fused(const __hip_bfloat16* __restrict__ qb,
                                                  const __hip_bfloat16* __restrict__ wb,
                                                  const __hip_bfloat16* __restrict__ khat,
                                                  const __hip_bfloat16* __restrict__ abT,
                                                  const __hip_bfloat16* __restrict__ vhi,
                                                  const float* __restrict__ G,
                                                  __hip_bfloat16* __restrict__ ohi,
                                                  float* __restrict__ opart,
                                                  float* __restrict__ mlbuf) {
  __shared__ __hip_bfloat16 Ms[64][72];
  __shared__ __hip_bfloat16 Ks[64][72];
  __shared__ __hip_bfloat16 Cs[64][72];
  __shared__ __hip_bfloat16 Vh[64][72];
  __shared__ __hip_bfloat16 Ps[64][72];
  const int task = blockIdx.x, bh = blockIdx.y;
  const int it = ATT_IT[task], j0 = ATT_J0[task], j1 = ATT_J1[task];
  const int slot = ATT_SLOT[task], part = ATT_PART[task];
  const int b = bh >> 4, h = bh & 15;
  const int tid = threadIdx.x, w = tid >> 6, lane = tid & 63;
  const int fr = lane & 15, kq = lane >> 4;
  const int row0 = w * 16 + kq * 4;
  const size_t hb = (size_t)bh * T_;
  const f32x4 zero = {0.f, 0.f, 0.f, 0.f};

  stage64(qb + (hb + it * 64) * DH, DH, Ks, tid);
  stage64(wb + (hb + it * 64) * DH, DH, Cs, tid);
  __syncthreads();
  const bf16x8 a0 = ldfrag(Ks, w, 0, fr, kq);
  const bf16x8 a1 = ldfrag(Ks, w, 1, fr, kq);
  f32x4 qw[4];
#pragma unroll
  for (int nb = 0; nb < 4; ++nb) {
    qw[nb] = MFMA_BF16(a0, ldfrag(Cs, nb, 0, fr, kq), zero);
    qw[nb] = MFMA_BF16(a1, ldfrag(Cs, nb, 1, fr, kq), qw[nb]);
  }
#pragma unroll
  for (int nb = 0; nb < 4; ++nb) {
    int col = nb * 16 + fr;
#pragma unroll
    for (int reg = 0; reg < 4; ++reg) {
      float v = -qw[nb][reg];
      if (col > row0 + reg) v = 0.f;
      Ms[row0 + reg][col] = __float2bfloat16(v);
    }
  }
  __syncthreads();
  const bf16x8 m0 = ldfrag(Ms, w, 0, fr, kq);
  const bf16x8 m1 = ldfrag(Ms, w, 1, fr, kq);

  float Gi[4];
#pragma unroll
  for (int reg = 0; reg < 4; ++reg) Gi[reg] = G[hb + it * 64 + row0 + reg];
  float mrow[4] = {-3e38f, -3e38f, -3e38f, -3e38f};
  float lrow[4] = {0.f, 0.f, 0.f, 0.f};
  f32x4 acc_o[4] = {zero, zero, zero, zero};
  const __hip_bfloat16* kh = khat + ((size_t)(bh * 8 + it)) * T_ * DH;

  for (int jt = j0; jt <= j1; ++jt) {
    __syncthreads();
    stage64(kh + (size_t)(jt * 64) * DH, DH, Ks, tid);
    stage64(abT + (hb + jt * 64) * T_ + it * 64, T_, Cs, tid);
    stage64(vhi + (size_t)bh * DH * T_ + jt * 64, T_, Vh, tid);
    __syncthreads();
    f32x4 acc[4];
#pragma unroll
    for (int nb = 0; nb < 4; ++nb) {
      acc[nb] = MFMA_BF16(a0, ldfrag(Ks, nb, 0, fr, kq), zero);
      acc[nb] = MFMA_BF16(a1, ldfrag(Ks, nb, 1, fr, kq), acc[nb]);
      acc[nb] = MFMA_BF16(m0, ldfrag(Cs, nb, 0, fr, kq), acc[nb]);
      acc[nb] = MFMA_BF16(m1, ldfrag(Cs, nb, 1, fr, kq), acc[nb]);
    }
    float gj[4];
#pragma unroll
    for (int nb = 0; nb < 4; ++nb) gj[nb] = G[hb + jt * 64 + nb * 16 + fr];
    const bool diag = (jt == it);
    float vv[4][4];
#pragma unroll
    for (int reg = 0; reg < 4; ++reg) {
      float tm = -3e38f;
#pragma unroll
      for (int nb = 0; nb < 4; ++nb) {
        float vx = acc[nb][reg] * 0.125f + Gi[reg] - gj[nb];
        if (diag && (nb * 16 + fr) > row0 + reg) vx = -3e38f;
        vv[nb][reg] = vx;
        tm = fmaxf(tm, vx);
      }
#pragma unroll
      for (int mm = 1; mm <= 8; mm <<= 1) tm = fmaxf(tm, __shfl_xor(tm, mm));
      float mnew = fmaxf(mrow[reg], tm);
      float sc = __expf(mrow[reg] - mnew);
      mrow[reg] = mnew;
      float tsum = 0.f;
#pragma unroll
      for (int nb = 0; nb < 4; ++nb) {
        float p = __expf(vv[nb][reg] - mnew);
        Ps[row0 + reg][nb * 16 + fr] = __float2bfloat16(p);
        tsum += p;
      }
#pragma unroll
      for (int mm = 1; mm <= 8; mm <<= 1) tsum += __shfl_xor(tsum, mm);
      lrow[reg] = lrow[reg] * sc + tsum;
#pragma unroll
      for (int nb = 0; nb < 4; ++nb) acc_o[nb][reg] *= sc;
    }
    __syncthreads();
    const bf16x8 p0 = ldfrag(Ps, w, 0, fr, kq);
    const bf16x8 p1 = ldfrag(Ps, w, 1, fr, kq);
#pragma unroll
    for (int nb = 0; nb < 4; ++nb) {
      acc_o[nb] = MFMA_BF16(p0, ldfrag(Vh, nb, 0, fr, kq), acc_o[nb]);
      acc_o[nb] = MFMA_BF16(p1, ldfrag(Vh, nb, 1, fr, kq), acc_o[nb]);
    }
  }
  if (part < 0) {
#pragma unroll
    for (int reg = 0; reg < 4; ++reg) {
      float inv = 1.f / lrow[reg];
      int i = it * 64 + row0 + reg;
#pragma unroll
      for (int nb = 0; nb < 4; ++nb) {
        int dd = nb * 16 + fr;
        size_t oi = ((size_t)(b * T_ + i)) * D_ + h * 64 + dd;
        ohi[oi] = __float2bfloat16(acc_o[nb][reg] * inv);
      }
    }
  } else {
    const size_t pb = ((size_t)(bh * 5 + slot) * 3 + part);
    float* Op = opart + pb * 4096;
    float* mlp = mlbuf + pb * 128;
#pragma unroll
    for (int reg = 0; reg < 4; ++reg) {
      int row = row0 + reg;
#pragma unroll
      for (int nb = 0; nb < 4; ++nb) {
        Op[row * 64 + nb * 16 + fr] = acc_o[nb][reg];
      }
      if (fr == 0) {
        mlp[row] = mrow[reg];
        mlp[64 + row] = lrow[reg];
      }
    }
  }
}

// ======================= merge split attn partials (rows 3-7, 2-3 parts) ==================
__global__ __launch_bounds__(256) void attn_merge(const float* __restrict__ opart,
                                                  const float* __restrict__ mlbuf,
                                                  __hip_bfloat16* __restrict__ ohi) {
  const int idx = blockIdx.x;                // bh*5 + slot, 0..159
  const int bh = idx / 5, slot = idx % 5, it = slot + 3;
  const int np = MRG_NP[slot];
  const int b = bh >> 4, h = bh & 15;
  const int tid = threadIdx.x;
  const int row = tid >> 2, dd0 = (tid & 3) * 16;
  const size_t base = (size_t)idx * 3;
  float mv = -3e38f;
  for (int p = 0; p < np; ++p) mv = fmaxf(mv, mlbuf[(base + p) * 128 + row]);
  float lsum = 0.f, e[3];
  for (int p = 0; p < np; ++p) {
    e[p] = __expf(mlbuf[(base + p) * 128 + row] - mv);
    lsum += mlbuf[(base + p) * 128 + 64 + row] * e[p];
  }
  const float inv = 1.f / lsum;
  const int i = it * 64 + row;
  const size_t ob = ((size_t)(b * T_ + i)) * D_ + h * 64;
#pragma unroll
  for (int u = 0; u < 16; ++u) {
    int dd = dd0 + u;
    float v = 0.f;
    for (int p = 0; p < np; ++p) v += opart[(base + p) * 4096 + row * 64 + dd] * e[p];
    ohi[ob + dd] = __float2bfloat16(v * inv);
  }
}

// ======================= launch =======================
extern "C" void kernel_launch(void* const* d_in, const int* in_sizes, int n_in,
                              void* d_out, int out_size, void* d_ws, size_t ws_size,
                              hipStream_t stream) {
  (void)in_sizes; (void)n_in; (void)out_size; (void)ws_size;
  const float* x     = (const float*)d_in[0];
  const float* Wq    = (const float*)d_in[1];
  const float* Wk    = (const float*)d_in[2];
  const float* Wv    = (const float*)d_in[3];
  const float* Wo    = (const float*)d_in[4];
  const float* wA    = (const float*)d_in[5];
  const float* wB    = (const float*)d_in[6];
  const float* convw = (const float*)d_in[7];
  const float* bw    = (const float*)d_in[8];
  const float* gw    = (const float*)d_in[9];
  const float* gb    = (const float*)d_in[10];
  const float* qnw   = (const float*)d_in[11];
  const float* knw   = (const float*)d_in[12];

  const size_t N1 = (size_t)BT_ * D_;
  const size_t NTT = (size_t)BH_ * T_ * T_;
  float* ws = (float*)d_ws;
  float* wTb   = ws;                       // [BH,T,dh] fp32
  float* ypart = wTb + N1;                 // [4][BT][64] fp32
  float* beta  = ypart + (size_t)4 * BT_ * 64;
  float* G     = beta + (size_t)BH_ * T_;
  float* opart = G + (size_t)BH_ * T_;     // [BH*5*3][4096] fp32 = 7.9 MB
  float* mlbuf = opart + (size_t)BH_ * 5 * 3 * 4096;   // [BH*5*3][128]
  __hip_bfloat16* qb16  = (__hip_bfloat16*)(mlbuf + (size_t)BH_ * 5 * 3 * 128);
  __hip_bfloat16* kb16  = qb16 + N1;
  __hip_bfloat16* wb16  = kb16 + N1;
  __hip_bfloat16* abT   = wb16 + N1;            // [BH,T(j),T(t)] bf16
  __hip_bfloat16* linvb = abT + NTT;            // [BH,8,64,64] bf16
  __hip_bfloat16* xhi   = linvb + (size_t)BH_ * 8 * 4096;
  __hip_bfloat16* xlo   = xhi + N1;
  __hip_bfloat16* obhi  = xlo + N1;
  __hip_bfloat16* woThi = obhi + N1;
  __hip_bfloat16* vhi   = woThi + N1;           // [BH,dh,T] bf16
  __hip_bfloat16* wcThi = vhi + N1;             // [64][D]
  __hip_bfloat16* wcTlo = wcThi + (size_t)64 * D_;
  __hip_bfloat16* khat  = wcTlo + (size_t)64 * D_;  // [BH,8,T,dh] bf16
  __hip_bfloat16* wqkvT = khat + (size_t)BH_ * 8 * T_ * DH;  // [3072][D]

  prep_k<<<1600, 256, 0, stream>>>(x, Wq, Wk, Wv, Wo, wA, bw, gw,
                                   xhi, xlo, wqkvT, woThi, wcThi, wcTlo);
  gemm_qkv_ycat<<<dim3(52, 16), 256, 0, stream>>>(xhi, xlo, wqkvT, wcThi, wcTlo,
                                                  qb16, kb16, vhi, ypart, qnw, knw);
  gate_wdir<<<BT_ + BH_, 512, 0, stream>>>(ypart, gb, wB, convw, beta, G, wTb, wb16);
  linv_k<<<dim3(8, BH_), 256, 0, stream>>>(wTb, beta, linvb);
  chain_k<<<dim3(8, BH_), 256, 0, stream>>>(kb16, wb16, linvb, beta, abT, khat);
  attn_fused<<<dim3(15, BH_), 256, 0, stream>>>(qb16, wb16, khat, abT, vhi, G,
                                                obhi, opart, mlbuf);
  attn_merge<<<160, 256, 0, stream>>>(opart, mlbuf, obhi);
  gemm_o<<<dim3(16, 16), 256, 0, stream>>>(obhi, woThi, (float*)d_out);
}

// Round 17
// 111.311 us; speedup vs baseline: 1.0743x; 1.0743x over previous
//
#include <hip/hip_runtime.h>
#include <hip/hip_bf16.h>
#include <math.h>

#define B_ 2
#define T_ 512
#define D_ 1024
#define H_ 16
#define R_ 32
#define DH 64
#define BT_ (B_*T_)
#define BH_ (B_*H_)

typedef __attribute__((ext_vector_type(8))) short bf16x8;
typedef __attribute__((ext_vector_type(4))) short s16x4;
typedef __attribute__((ext_vector_type(4))) float f32x4;

#define MFMA_BF16(a, b, c) __builtin_amdgcn_mfma_f32_16x16x32_bf16(a, b, c, 0, 0, 0)

static __device__ __forceinline__ short bf16s(float v) {
  __hip_bfloat16 b = __float2bfloat16(v);
  return *reinterpret_cast<short*>(&b);
}
static __device__ __forceinline__ float b2f(__hip_bfloat16 h) { return __bfloat162float(h); }

// attn task table (R15-winning): 12 tasks/bh; rows 0-3 single, rows 4-7 split 2-way
__constant__ int ATT_IT[12]   = {0,1,2,3,4,4,5,5,6,6,7,7};
__constant__ int ATT_J0[12]   = {0,0,0,0,0,3,0,3,0,4,0,4};
__constant__ int ATT_J1[12]   = {0,1,2,3,2,4,2,5,3,6,3,7};
__constant__ int ATT_PART[12] = {-1,-1,-1,-1,0,1,0,1,0,1,0,1};

// ---- padded-tile helpers ([72] pad = 144B stride, conflict-free) ----
__device__ __forceinline__ bf16x8 ldfrag(const __hip_bfloat16 s[][72], int b16, int kb, int fr, int kq) {
  return *(const bf16x8*)&s[b16 * 16 + fr][kb * 32 + kq * 8];
}
__device__ __forceinline__ void stage64(const __hip_bfloat16* __restrict__ g, int ldg,
                                        __hip_bfloat16 s[][72], int tid) {
#pragma unroll
  for (int l = 0; l < 2; ++l) {
    int f = tid + l * 256;
    int r = f >> 3, c = (f & 7) << 3;
    *(int4*)&s[r][c] = *(const int4*)&g[(size_t)r * ldg + c];
  }
}

// ---- global_load_lds 16B direct-to-LDS (GEMMs only; linear dest per rule #21) ----
typedef const __attribute__((address_space(1))) void* as1cv;
typedef __attribute__((address_space(3))) void* as3v;
__device__ __forceinline__ void gl16(const __hip_bfloat16* g, __hip_bfloat16* l) {
  __builtin_amdgcn_global_load_lds((as1cv)g, (as3v)l, 16, 0, 0);
}
__device__ __forceinline__ void stage64s(const __hip_bfloat16* __restrict__ g, int ldg,
                                         __hip_bfloat16* s, int tid) {
#pragma unroll
  for (int i = 0; i < 2; ++i) {
    int chunk = tid + i * 256;
    int r = chunk >> 3, c8 = (chunk & 7) ^ (r & 7);
    gl16(g + (size_t)r * ldg + c8 * 8, s + chunk * 8);
  }
}
__device__ __forceinline__ bf16x8 ldfragS(const __hip_bfloat16* s, int b16, int half, int fr, int kq) {
  int r = b16 * 16 + fr;
  int col8 = ((kq + half * 4) ^ (r & 7)) * 8;
  return *(const bf16x8*)&s[r * 64 + col8];
}

// ======================= prep: split x (hi/lo), transpose weights (hi), splitcat ==========
__global__ __launch_bounds__(256) void prep_k(const float* __restrict__ x,
                                              const float* __restrict__ Wq,
                                              const float* __restrict__ Wk,
                                              const float* __restrict__ Wv,
                                              const float* __restrict__ Wo,
                                              const float* __restrict__ wA,
                                              const float* __restrict__ bw,
                                              const float* __restrict__ gw,
                                              __hip_bfloat16* __restrict__ xhi,
                                              __hip_bfloat16* __restrict__ xlo,
                                              __hip_bfloat16* __restrict__ wqkvT,  // [3072][D]
                                              __hip_bfloat16* __restrict__ woT,    // [1024][D]
                                              __hip_bfloat16* __restrict__ wcThi,
                                              __hip_bfloat16* __restrict__ wcTlo) {
  __shared__ float tile[64][65];
  const int bid = blockIdx.x, tid = threadIdx.x;
  if (bid < 512) {
    int i8 = bid * 256 + tid;
    float4 v0 = ((const float4*)x)[i8 * 2];
    float4 v1 = ((const float4*)x)[i8 * 2 + 1];
    float c[8] = {v0.x, v0.y, v0.z, v0.w, v1.x, v1.y, v1.z, v1.w};
    bf16x8 ph, pl;
#pragma unroll
    for (int u = 0; u < 8; ++u) {
      __hip_bfloat16 h = __float2bfloat16(c[u]);
      ph[u] = *reinterpret_cast<short*>(&h);
      pl[u] = bf16s(c[u] - __bfloat162float(h));
    }
    *(bf16x8*)&xhi[(size_t)i8 * 8] = ph;
    *(bf16x8*)&xlo[(size_t)i8 * 8] = pl;
  } else if (bid < 1536) {
    const int zz = (bid - 512) >> 8, idx = (bid - 512) & 255;
    const float* Wm = (zz == 0) ? Wq : (zz == 1) ? Wk : (zz == 2) ? Wv : Wo;
    __hip_bfloat16* thi = (zz < 3) ? (wqkvT + (size_t)zz * 1024 * D_) : woT;
    const int bn = (idx & 15) * 64, bk = (idx >> 4) * 64;
#pragma unroll
    for (int l = 0; l < 4; ++l) {
      int f = tid + l * 256; int r = f >> 4, c = (f & 15) << 2;
      *(float4*)&tile[r][c] = *(const float4*)&Wm[(size_t)(bk + r) * D_ + bn + c];
    }
    __syncthreads();
#pragma unroll
    for (int l = 0; l < 4; ++l) {
      int f = tid + l * 256; int n = f >> 4, k0 = (f & 15) << 2;
      s16x4 ph;
#pragma unroll
      for (int u = 0; u < 4; ++u) ph[u] = bf16s(tile[k0 + u][n]);
      *(s16x4*)&thi[(size_t)(bn + n) * D_ + bk + k0] = ph;
    }
  } else {
    int n = bid - 1536;
    for (int k = tid; k < D_; k += 256) {
      float v;
      if (n < 32) v = wA[(size_t)k * R_ + n];
      else if (n < 48) v = bw[(size_t)k * H_ + (n - 32)];
      else v = gw[(size_t)k * H_ + (n - 48)];
      __hip_bfloat16 h = __float2bfloat16(v);
      wcThi[(size_t)n * D_ + k] = h;
      wcTlo[(size_t)n * D_ + k] = __float2bfloat16(v - __bfloat162float(h));
    }
  }
}

// ======================= merged QKV projection + ycat partials =======================
__global__ __launch_bounds__(256) void gemm_qkv_ycat(const __hip_bfloat16* __restrict__ ah,
                                                     const __hip_bfloat16* __restrict__ al,
                                                     const __hip_bfloat16* __restrict__ bT,
                                                     const __hip_bfloat16* __restrict__ wch,
                                                     const __hip_bfloat16* __restrict__ wcl,
                                                     __hip_bfloat16* __restrict__ qb,
                                                     __hip_bfloat16* __restrict__ kb,
                                                     __hip_bfloat16* __restrict__ vhi,
                                                     float* __restrict__ ypart,
                                                     const float* __restrict__ qnw,
                                                     const float* __restrict__ knw) {
  __shared__ __align__(16) char smem[43008];   // 42 KB union
  const int bx = blockIdx.x, bm = blockIdx.y * 64;
  const int tid = threadIdx.x, w = tid >> 6, lane = tid & 63;
  const int fr = lane & 15, kq = lane >> 4;
  const f32x4 zf = {0.f, 0.f, 0.f, 0.f};
  f32x4 acc[4] = {zf, zf, zf, zf};

  if (bx < 48) {
    __hip_bfloat16* As = (__hip_bfloat16*)smem;              // [2][64][64]
    __hip_bfloat16* Bs = As + 2 * 4096;                      // [2][64][64]
    __hip_bfloat16 (*Lt)[72] = (__hip_bfloat16(*)[72])(Bs + 2 * 4096);  // [64][72]
    const int bn = bx * 64;
    const __hip_bfloat16* ap = ah + (size_t)bm * D_;
    const __hip_bfloat16* bp = bT + (size_t)bn * D_;
    stage64s(ap, D_, As, tid);
    stage64s(bp, D_, Bs, tid);
    __syncthreads();
    for (int t = 0; t < 16; ++t) {
      const int cur = t & 1;
      if (t < 15) {
        stage64s(ap + (t + 1) * 64, D_, As + (cur ^ 1) * 4096, tid);
        stage64s(bp + (t + 1) * 64, D_, Bs + (cur ^ 1) * 4096, tid);
      }
      bf16x8 a0 = ldfragS(As + cur * 4096, w, 0, fr, kq);
      bf16x8 a1 = ldfragS(As + cur * 4096, w, 1, fr, kq);
#pragma unroll
      for (int n = 0; n < 4; ++n) {
        acc[n] = MFMA_BF16(a0, ldfragS(Bs + cur * 4096, n, 0, fr, kq), acc[n]);
        acc[n] = MFMA_BF16(a1, ldfragS(Bs + cur * 4096, n, 1, fr, kq), acc[n]);
      }
      __syncthreads();
    }
    if (bn < 2048) {
      float rs[4];
#pragma unroll
      for (int reg = 0; reg < 4; ++reg) {
        float s = 0.f;
#pragma unroll
        for (int n = 0; n < 4; ++n) s += acc[n][reg] * acc[n][reg];
#pragma unroll
        for (int mm = 1; mm <= 8; mm <<= 1) s += __shfl_xor(s, mm);
        rs[reg] = rsqrtf(s * (1.f / DH) + 1e-5f);
      }
      const bool isq = (bn < 1024);
      __hip_bfloat16* outp = isq ? qb : kb;
#pragma unroll
      for (int n = 0; n < 4; ++n) {
        int gn = bn + n * 16 + fr;
        int dd = gn & 63, h = (gn & 1023) >> 6;
        float nw = (isq ? qnw : knw)[dd];
#pragma unroll
        for (int reg = 0; reg < 4; ++reg) {
          int gm = bm + w * 16 + kq * 4 + reg;
          int bb = gm >> 9, tt = gm & 511;
          outp[(((size_t)(bb * H_ + h)) * T_ + tt) * DH + dd] =
              __float2bfloat16(acc[n][reg] * rs[reg] * nw);
        }
      }
    } else {
      const int row0 = w * 16 + kq * 4;
#pragma unroll
      for (int n = 0; n < 4; ++n) {
        int dd = n * 16 + fr;
#pragma unroll
        for (int reg = 0; reg < 4; ++reg) Lt[dd][row0 + reg] = __float2bfloat16(acc[n][reg]);
      }
      __syncthreads();
      const int b = bm >> 9, t0 = bm & 511, h = (bn - 2048) >> 6;
      const size_t base = ((size_t)(b * H_ + h)) * DH * T_;
#pragma unroll
      for (int l = 0; l < 2; ++l) {
        int f = tid + l * 256;
        int dd = f >> 3, tq = (f & 7) * 8;
        *(bf16x8*)&vhi[base + (size_t)dd * T_ + t0 + tq] = *(const bf16x8*)&Lt[dd][tq];
      }
    }
  } else {
    __hip_bfloat16 (*Ah)[72] = (__hip_bfloat16(*)[72])smem;
    __hip_bfloat16 (*Al)[72] = (__hip_bfloat16(*)[72])(smem + 9216);
    __hip_bfloat16 (*Bh)[72] = (__hip_bfloat16(*)[72])(smem + 18432);
    __hip_bfloat16 (*Bl)[72] = (__hip_bfloat16(*)[72])(smem + 27648);
    const int z = bx - 48;
    float* C = ypart + (size_t)z * (BT_ * 64);
    for (int k0 = z * 256; k0 < z * 256 + 256; k0 += 64) {
      __syncthreads();
      stage64(ah + (size_t)bm * D_ + k0, D_, Ah, tid);
      stage64(al + (size_t)bm * D_ + k0, D_, Al, tid);
      stage64(wch + k0, D_, Bh, tid);
      stage64(wcl + k0, D_, Bl, tid);
      __syncthreads();
      bf16x8 ah0 = ldfrag(Ah, w, 0, fr, kq), ah1 = ldfrag(Ah, w, 1, fr, kq);
      bf16x8 al0 = ldfrag(Al, w, 0, fr, kq), al1 = ldfrag(Al, w, 1, fr, kq);
#pragma unroll
      for (int nb = 0; nb < 4; ++nb) {
        bf16x8 b0 = ldfrag(Bh, nb, 0, fr, kq), b1 = ldfrag(Bh, nb, 1, fr, kq);
        bf16x8 c0 = ldfrag(Bl, nb, 0, fr, kq), c1 = ldfrag(Bl, nb, 1, fr, kq);
        acc[nb] = MFMA_BF16(ah0, b0, acc[nb]); acc[nb] = MFMA_BF16(ah1, b1, acc[nb]);
        acc[nb] = MFMA_BF16(ah0, c0, acc[nb]); acc[nb] = MFMA_BF16(ah1, c1, acc[nb]);
        acc[nb] = MFMA_BF16(al0, b0, acc[nb]); acc[nb] = MFMA_BF16(al1, b1, acc[nb]);
      }
    }
#pragma unroll
    for (int nb = 0; nb < 4; ++nb) {
      int n = nb * 16 + fr;
#pragma unroll
      for (int reg = 0; reg < 4; ++reg) {
        int m = bm + w * 16 + kq * 4 + reg;
        C[(size_t)m * 64 + n] = acc[nb][reg];
      }
    }
  }
}

// ======================= Wo projection: dbuf 1-pass bf16 -> fp32 =======================
__global__ __launch_bounds__(256) void gemm_o(const __hip_bfloat16* __restrict__ ah,
                                              const __hip_bfloat16* __restrict__ bT,
                                              float* __restrict__ C) {
  __shared__ __hip_bfloat16 As[2][64][64];
  __shared__ __hip_bfloat16 Bs[2][64][64];
  const int bm = blockIdx.y * 64, bn = blockIdx.x * 64;
  const int tid = threadIdx.x, w = tid >> 6, lane = tid & 63;
  const int fr = lane & 15, kq = lane >> 4;
  const f32x4 zf = {0.f, 0.f, 0.f, 0.f};
  f32x4 acc[4] = {zf, zf, zf, zf};
  const __hip_bfloat16* ap = ah + (size_t)bm * D_;
  const __hip_bfloat16* bp = bT + (size_t)bn * D_;
  stage64s(ap, D_, &As[0][0][0], tid);
  stage64s(bp, D_, &Bs[0][0][0], tid);
  __syncthreads();
  for (int t = 0; t < 16; ++t) {
    const int cur = t & 1;
    if (t < 15) {
      stage64s(ap + (t + 1) * 64, D_, &As[cur ^ 1][0][0], tid);
      stage64s(bp + (t + 1) * 64, D_, &Bs[cur ^ 1][0][0], tid);
    }
    bf16x8 a0 = ldfragS(&As[cur][0][0], w, 0, fr, kq);
    bf16x8 a1 = ldfragS(&As[cur][0][0], w, 1, fr, kq);
#pragma unroll
    for (int n = 0; n < 4; ++n) {
      acc[n] = MFMA_BF16(a0, ldfragS(&Bs[cur][0][0], n, 0, fr, kq), acc[n]);
      acc[n] = MFMA_BF16(a1, ldfragS(&Bs[cur][0][0], n, 1, fr, kq), acc[n]);
    }
    __syncthreads();
  }
#pragma unroll
  for (int n = 0; n < 4; ++n) {
    int gn = bn + n * 16 + fr;
#pragma unroll
    for (int reg = 0; reg < 4; ++reg) {
      int gm = bm + w * 16 + kq * 4 + reg;
      C[(size_t)gm * D_ + gn] = acc[n][reg];
    }
  }
}

// ======================= merged gates + wdir (both read ypart) =======================
__global__ __launch_bounds__(512) void gate_wdir(const float* __restrict__ ypart,
                                                 const float* __restrict__ gb,
                                                 const float* __restrict__ wB,
                                                 const float* __restrict__ convw,
                                                 float* __restrict__ beta,
                                                 float* __restrict__ G,
                                                 float* __restrict__ wT,
                                                 __hip_bfloat16* __restrict__ wb16) {
  __shared__ float shm[T_];
  const int bid = blockIdx.x, tid = threadIdx.x;
  if (bid < BT_) {
    int bt = bid, b = bt / T_, t = bt - b * T_;
    float* wl = shm;                      // [3][32]
    if (tid < 3 * R_) {
      int row = tid / R_, r = tid - row * R_;
      int ts = t - row;
      float a = 0.f;
      if (ts >= 0) {
#pragma unroll
        for (int z = 0; z < 4; ++z)
          a += ypart[(size_t)z * (BT_ * 64) + (size_t)(b * T_ + ts) * 64 + r];
      }
      wl[row * R_ + r] = a;
    }
    __syncthreads();
#pragma unroll
    for (int half = 0; half < 2; ++half) {
      int col = tid + half * 512;
      float f0 = 0.f, f1 = 0.f, f2 = 0.f;
      for (int r = 0; r < R_; ++r) {
        float wb = wB[(size_t)r * D_ + col];
        f0 += wl[0 * R_ + r] * wb; f1 += wl[1 * R_ + r] * wb; f2 += wl[2 * R_ + r] * wb;
      }
      float y = f2 * convw[col * 3 + 0] + f1 * convw[col * 3 + 1] + f0 * convw[col * 3 + 2];
      float s = y / (1.f + expf(-y));
      float ss = s * s;
#pragma unroll
      for (int m = 32; m >= 1; m >>= 1) ss += __shfl_xor(ss, m);
      float outv = s * rsqrtf(ss + 1e-12f);
      int h = col >> 6, dd = col & 63;
      size_t o = (((size_t)(b * H_ + h)) * T_ + t) * DH + dd;
      wT[o] = outv;
      wb16[o] = __float2bfloat16(outv);
    }
  } else {
    int bh = bid - BT_, b = bh >> 4, h = bh & 15, t = tid;
    int bt = b * T_ + t;
    float by = 0.f, gy = gb[h];
#pragma unroll
    for (int z = 0; z < 4; ++z) {
      const float* yp = ypart + (size_t)z * (BT_ * 64) + (size_t)bt * 64;
      by += yp[32 + h];
      gy += yp[48 + h];
    }
    beta[(size_t)bh * T_ + t] = 2.f / (1.f + expf(-by));
    shm[t] = fminf(gy, 0.f) - log1pf(expf(-fabsf(gy)));
    __syncthreads();
    for (int off = 1; off < T_; off <<= 1) {
      float v = (t >= off) ? shm[t - off] : 0.f;
      __syncthreads();
      shm[t] += v;
      __syncthreads();
    }
    G[(size_t)bh * T_ + t] = shm[t];
  }
}

// ======================= unit-lower inverse, 8-row blocked substitution =======================
__global__ __launch_bounds__(256) void linv_k(const float* __restrict__ wT,
                                              const float* __restrict__ beta,
                                              __hip_bfloat16* __restrict__ linv) {
  __shared__ float Wsh[64][68];
  __shared__ float Csh[64][65];
  __shared__ float Li[64][68];
  __shared__ float bI[64];
  const int I = blockIdx.x, bhx = blockIdx.y;
  const int tid = threadIdx.x;
#pragma unroll
  for (int l = 0; l < 4; ++l) {
    int f = tid + l * 256; int r = f >> 4, c = (f & 15) << 2;
    *(float4*)&Wsh[r][c] = *(const float4*)&wT[((size_t)bhx * T_ + I * 64 + r) * DH + c];
  }
  if (tid < 64) bI[tid] = beta[(size_t)bhx * T_ + I * 64 + tid];
#pragma unroll
  for (int l = 0; l < 16; ++l) {
    int e = tid + l * 256; int r = e >> 6, c = e & 63;
    Li[r][c] = (r == c) ? 1.f : 0.f;
  }
  __syncthreads();
  const int tm = (tid >> 4) << 2, tn = (tid & 15) << 2;
  float cc[4][4] = {};
  for (int dd = 0; dd < 64; ++dd) {
    float a0 = Wsh[tm + 0][dd], a1 = Wsh[tm + 1][dd], a2 = Wsh[tm + 2][dd], a3 = Wsh[tm + 3][dd];
    float b0 = Wsh[tn + 0][dd], b1 = Wsh[tn + 1][dd], b2 = Wsh[tn + 2][dd], b3 = Wsh[tn + 3][dd];
    cc[0][0] += a0 * b0; cc[0][1] += a0 * b1; cc[0][2] += a0 * b2; cc[0][3] += a0 * b3;
    cc[1][0] += a1 * b0; cc[1][1] += a1 * b1; cc[1][2] += a1 * b2; cc[1][3] += a1 * b3;
    cc[2][0] += a2 * b0; cc[2][1] += a2 * b1; cc[2][2] += a2 * b2; cc[2][3] += a2 * b3;
    cc[3][0] += a3 * b0; cc[3][1] += a3 * b1; cc[3][2] += a3 * b2; cc[3][3] += a3 * b3;
  }
#pragma unroll
  for (int ii = 0; ii < 4; ++ii)
#pragma unroll
    for (int jj = 0; jj < 4; ++jj)
      Csh[tm + ii][tn + jj] = (tm + ii > tn + jj) ? cc[ii][jj] * bI[tn + jj] : 0.f;
  __syncthreads();
  const int sL = tid & 63, g = tid >> 6;
  for (int r0 = 0; r0 < 64; r0 += 8) {
    float a[8];
#pragma unroll
    for (int u = 0; u < 8; ++u) a[u] = Li[r0 + u][sL];
    __syncthreads();
#pragma unroll
    for (int u = 1; u < 8; ++u)
#pragma unroll
      for (int s = 0; s < u; ++s) a[u] -= Csh[r0 + u][r0 + s] * a[s];
    if (g == 0) {
#pragma unroll
      for (int u = 1; u < 8; ++u) Li[r0 + u][sL] = a[u];
    }
    for (int r2 = r0 + 8 + g; r2 < 64; r2 += 4) {
      float acc = Li[r2][sL];
#pragma unroll
      for (int u = 0; u < 8; ++u) acc -= Csh[r2][r0 + u] * a[u];
      Li[r2][sL] = acc;
    }
    __syncthreads();
  }
#pragma unroll
  for (int l = 0; l < 4; ++l) {
    int f = tid + l * 256; int r = f >> 4, c0 = (f & 15) << 2;
    s16x4 p;
    p.x = bf16s(Li[r][c0 + 0]); p.y = bf16s(Li[r][c0 + 1]);
    p.z = bf16s(Li[r][c0 + 2]); p.w = bf16s(Li[r][c0 + 3]);
    *(s16x4*)&linv[((size_t)(bhx * 8 + I)) * 4096 + r * 64 + c0] = p;
  }
}

// ======================= WY chain, khat-first, 3 barriers/iter =======================
__global__ __launch_bounds__(256) void chain_k(const __hip_bfloat16* __restrict__ kb,
                                               const __hip_bfloat16* __restrict__ wb,
                                               const __hip_bfloat16* __restrict__ linv,
                                               const float* __restrict__ beta,
                                               __hip_bfloat16* __restrict__ abT,
                                               __hip_bfloat16* __restrict__ khat) {
  __shared__ __hip_bfloat16 Kb[64][72];
  __shared__ __hip_bfloat16 Ws[64][72];
  __shared__ __hip_bfloat16 WsT[64][72];
  __shared__ __hip_bfloat16 Ls[64][72];
  __shared__ __hip_bfloat16 Kh[64][72];
  __shared__ __hip_bfloat16 Ps[64][72];
  __shared__ __hip_bfloat16 Xs[64][72];
  __shared__ float bI[64];
  const int ch = blockIdx.x, bhx = blockIdx.y;
  const int tid = threadIdx.x, w = tid >> 6, lane = tid & 63;
  const int fr = lane & 15, kq = lane >> 4;
  const int jr = w * 16 + kq * 4;
  const size_t hb = (size_t)bhx * T_;
  const f32x4 zf = {0.f, 0.f, 0.f, 0.f};

  stage64(kb + (hb + ch * 64) * DH, DH, Kb, tid);
  f32x4 macc[4] = {zf, zf, zf, zf};
  __syncthreads();                                            // Kb visible

  for (int I = ch; I < 8; ++I) {
    stage64(wb + (hb + I * 64) * DH, DH, Ws, tid);
    stage64(linv + ((size_t)(bhx * 8 + I)) * 4096, 64, Ls, tid);
    if (tid < 64) bI[tid] = beta[hb + I * 64 + tid];
#pragma unroll
    for (int nb = 0; nb < 4; ++nb) {
      int d = nb * 16 + fr;
#pragma unroll
      for (int reg = 0; reg < 4; ++reg)
        Kh[jr + reg][d] = __float2bfloat16(b2f(Kb[jr + reg][d]) - macc[nb][reg]);
    }
    __syncthreads();                                           // B2: stages + Kh visible
#pragma unroll
    for (int l = 0; l < 2; ++l) {
      int f = tid + l * 256;
      int r = f >> 3, c = (f & 7) << 3;
      *(int4*)&khat[(((size_t)(bhx * 8 + I)) * T_ + ch * 64 + r) * DH + c] = *(const int4*)&Kh[r][c];
    }
#pragma unroll
    for (int l = 0; l < 16; ++l) {
      int e = tid + l * 256;
      int t = e >> 6, d = e & 63;
      WsT[d][t] = Ws[t][d];
    }
    bf16x8 kh0 = ldfrag(Kh, w, 0, fr, kq), kh1 = ldfrag(Kh, w, 1, fr, kq);
    f32x4 pt[4];
#pragma unroll
    for (int nb = 0; nb < 4; ++nb) {
      pt[nb] = MFMA_BF16(kh0, ldfrag(Ws, nb, 0, fr, kq), zf);
      pt[nb] = MFMA_BF16(kh1, ldfrag(Ws, nb, 1, fr, kq), pt[nb]);
    }
#pragma unroll
    for (int nb = 0; nb < 4; ++nb) {
      int t = nb * 16 + fr;
#pragma unroll
      for (int reg = 0; reg < 4; ++reg) {
        float v = pt[nb][reg];
        if (I == ch && t <= jr + reg) v = 0.f;
        Ps[jr + reg][t] = __float2bfloat16(v);
      }
    }
    __syncthreads();                                           // B3: Ps & WsT visible
    bf16x8 la0 = ldfrag(Ls, w, 0, fr, kq), la1 = ldfrag(Ls, w, 1, fr, kq);
    f32x4 av[4];
#pragma unroll
    for (int nb = 0; nb < 4; ++nb) {
      av[nb] = MFMA_BF16(la0, ldfrag(Ps, nb, 0, fr, kq), zf);
      av[nb] = MFMA_BF16(la1, ldfrag(Ps, nb, 1, fr, kq), av[nb]);
    }
#pragma unroll
    for (int nb = 0; nb < 4; ++nb) {
      s16x4 p;
      p.x = bf16s(bI[jr + 0] * av[nb][0]);
      p.y = bf16s(bI[jr + 1] * av[nb][1]);
      p.z = bf16s(bI[jr + 2] * av[nb][2]);
      p.w = bf16s(bI[jr + 3] * av[nb][3]);
      *(s16x4*)&Xs[nb * 16 + fr][jr] = p;
    }
    __syncthreads();                                           // B4: Xs visible; all Ws/Ls/Kh/bI readers done
#pragma unroll
    for (int l = 0; l < 2; ++l) {
      int f = tid + l * 256;
      int r = f >> 3, c = (f & 7) << 3;
      *(int4*)&abT[(hb + ch * 64 + r) * T_ + I * 64 + c] = *(const int4*)&Xs[r][c];
    }
    bf16x8 xa0 = ldfrag(Xs, w, 0, fr, kq), xa1 = ldfrag(Xs, w, 1, fr, kq);
#pragma unroll
    for (int nb = 0; nb < 4; ++nb) {
      macc[nb] = MFMA_BF16(xa0, ldfrag(WsT, nb, 0, fr, kq), macc[nb]);
      macc[nb] = MFMA_BF16(xa1, ldfrag(WsT, nb, 1, fr, kq), macc[nb]);
    }
  }
}

// ======================= fused attention, task-balanced (12 tasks/bh) =====================
__global__ __launch_bounds__(256) void attn_fused(const __hip_bfloat16* __restrict__ qb,
                                                  const __hip_bfloat16* __restrict__ wb,
                                                  const __hip_bfloat16* __restrict__ khat,
                                                  const __hip_bfloat16* __restrict__ abT,
                                                  const __hip_bfloat16* __restrict__ vhi,
                                                  const float* __restrict__ G,
                                                  __hip_bfloat16* __restrict__ ohi,
                                                  float* __restrict__ opart,
                                                  float* __restrict__ mlbuf) {
  __shared__ __hip_bfloat16 Ms[64][72];
  __shared__ __hip_bfloat16 Ks[64][72];
  __shared__ __hip_bfloat16 Cs[64][72];
  __shared__ __hip_bfloat16 Vh[64][72];
  __shared__ __hip_bfloat16 Ps[64][72];
  const int task = blockIdx.x, bh = blockIdx.y;
  const int it = ATT_IT[task], j0 = ATT_J0[task], j1 = ATT_J1[task], part = ATT_PART[task];
  const int b = bh >> 4, h = bh & 15;
  const int tid = threadIdx.x, w = tid >> 6, lane = tid & 63;
  const int fr = lane & 15, kq = lane >> 4;
  const int row0 = w * 16 + kq * 4;
  const size_t hb = (size_t)bh * T_;
  const f32x4 zero = {0.f, 0.f, 0.f, 0.f};

  stage64(qb + (hb + it * 64) * DH, DH, Ks, tid);
  stage64(wb + (hb + it * 64) * DH, DH, Cs, tid);
  __syncthreads();
  const bf16x8 a0 = ldfrag(Ks, w, 0, fr, kq);
  const bf16x8 a1 = ldfrag(Ks, w, 1, fr, kq);
  f32x4 qw[4];
#pragma unroll
  for (int nb = 0; nb < 4; ++nb) {
    qw[nb] = MFMA_BF16(a0, ldfrag(Cs, nb, 0, fr, kq), zero);
    qw[nb] = MFMA_BF16(a1, ldfrag(Cs, nb, 1, fr, kq), qw[nb]);
  }
#pragma unroll
  for (int nb = 0; nb < 4; ++nb) {
    int col = nb * 16 + fr;
#pragma unroll
    for (int reg = 0; reg < 4; ++reg) {
      float v = -qw[nb][reg];
      if (col > row0 + reg) v = 0.f;
      Ms[row0 + reg][col] = __float2bfloat16(v);
    }
  }
  __syncthreads();
  const bf16x8 m0 = ldfrag(Ms, w, 0, fr, kq);
  const bf16x8 m1 = ldfrag(Ms, w, 1, fr, kq);

  float Gi[4];
#pragma unroll
  for (int reg = 0; reg < 4; ++reg) Gi[reg] = G[hb + it * 64 + row0 + reg];
  float mrow[4] = {-3e38f, -3e38f, -3e38f, -3e38f};
  float lrow[4] = {0.f, 0.f, 0.f, 0.f};
  f32x4 acc_o[4] = {zero, zero, zero, zero};
  const __hip_bfloat16* kh = khat + ((size_t)(bh * 8 + it)) * T_ * DH;

  for (int jt = j0; jt <= j1; ++jt) {
    __syncthreads();
    stage64(kh + (size_t)(jt * 64) * DH, DH, Ks, tid);
    stage64(abT + (hb + jt * 64) * T_ + it * 64, T_, Cs, tid);
    stage64(vhi + (size_t)bh * DH * T_ + jt * 64, T_, Vh, tid);
    __syncthreads();
    f32x4 acc[4];
#pragma unroll
    for (int nb = 0; nb < 4; ++nb) {
      acc[nb] = MFMA_BF16(a0, ldfrag(Ks, nb, 0, fr, kq), zero);
      acc[nb] = MFMA_BF16(a1, ldfrag(Ks, nb, 1, fr, kq), acc[nb]);
      acc[nb] = MFMA_BF16(m0, ldfrag(Cs, nb, 0, fr, kq), acc[nb]);
      acc[nb] = MFMA_BF16(m1, ldfrag(Cs, nb, 1, fr, kq), acc[nb]);
    }
    float gj[4];
#pragma unroll
    for (int nb = 0; nb < 4; ++nb) gj[nb] = G[hb + jt * 64 + nb * 16 + fr];
    const bool diag = (jt == it);
    float vv[4][4];
#pragma unroll
    for (int reg = 0; reg < 4; ++reg) {
      float tm = -3e38f;
#pragma unroll
      for (int nb = 0; nb < 4; ++nb) {
        float vx = acc[nb][reg] * 0.125f + Gi[reg] - gj[nb];
        if (diag && (nb * 16 + fr) > row0 + reg) vx = -3e38f;
        vv[nb][reg] = vx;
        tm = fmaxf(tm, vx);
      }
#pragma unroll
      for (int mm = 1; mm <= 8; mm <<= 1) tm = fmaxf(tm, __shfl_xor(tm, mm));
      float mnew = fmaxf(mrow[reg], tm);
      float sc = __expf(mrow[reg] - mnew);
      mrow[reg] = mnew;
      float tsum = 0.f;
#pragma unroll
      for (int nb = 0; nb < 4; ++nb) {
        float p = __expf(vv[nb][reg] - mnew);
        Ps[row0 + reg][nb * 16 + fr] = __float2bfloat16(p);
        tsum += p;
      }
#pragma unroll
      for (int mm = 1; mm <= 8; mm <<= 1) tsum += __shfl_xor(tsum, mm);
      lrow[reg] = lrow[reg] * sc + tsum;
#pragma unroll
      for (int nb = 0; nb < 4; ++nb) acc_o[nb][reg] *= sc;
    }
    __syncthreads();
    const bf16x8 p0 = ldfrag(Ps, w, 0, fr, kq);
    const bf16x8 p1 = ldfrag(Ps, w, 1, fr, kq);
#pragma unroll
    for (int nb = 0; nb < 4; ++nb) {
      acc_o[nb] = MFMA_BF16(p0, ldfrag(Vh, nb, 0, fr, kq), acc_o[nb]);
      acc_o[nb] = MFMA_BF16(p1, ldfrag(Vh, nb, 1, fr, kq), acc_o[nb]);
    }
  }
  if (part < 0) {
#pragma unroll
    for (int reg = 0; reg < 4; ++reg) {
      float inv = 1.f / lrow[reg];
      int i = it * 64 + row0 + reg;
#pragma unroll
      for (int nb = 0; nb < 4; ++nb) {
        int dd = nb * 16 + fr;
        size_t oi = ((size_t)(b * T_ + i)) * D_ + h * 64 + dd;
        ohi[oi] = __float2bfloat16(acc_o[nb][reg] * inv);
      }
    }
  } else {
    const size_t pb = ((size_t)(bh * 4 + (it - 4)) * 2 + part);
    float* Op = opart + pb * 4096;
    float* mlp = mlbuf + pb * 128;
#pragma unroll
    for (int reg = 0; reg < 4; ++reg) {
      int row = row0 + reg;
#pragma unroll
      for (int nb = 0; nb < 4; ++nb) {
        Op[row * 64 + nb * 16 + fr] = acc_o[nb][reg];
      }
      if (fr == 0) {
        mlp[row] = mrow[reg];
        mlp[64 + row] = lrow[reg];
      }
    }
  }
}

// ======================= merge split attn partials (rows 4-7) =======================
__global__ __launch_bounds__(256) void attn_merge(const float* __restrict__ opart,
                                                  const float* __restrict__ mlbuf,
                                                  __hip_bfloat16* __restrict__ ohi) {
  const int idx = blockIdx.x;                // bh*4 + (it-4), 0..127
  const int bh = idx >> 2, it = (idx & 3) + 4;
  const int b = bh >> 4, h = bh & 15;
  const int tid = threadIdx.x;
  const float* O0 = opart + ((size_t)idx * 2 + 0) * 4096;
  const float* O1 = opart + ((size_t)idx * 2 + 1) * 4096;
  const float* ml0 = mlbuf + ((size_t)idx * 2 + 0) * 128;
  const float* ml1 = mlbuf + ((size_t)idx * 2 + 1) * 128;
  const int row = tid >> 2, dd0 = (tid & 3) * 16;
  const float m0 = ml0[row], l0 = ml0[64 + row];
  const float m1 = ml1[row], l1 = ml1[64 + row];
  const float m = fmaxf(m0, m1);
  const float e0 = __expf(m0 - m), e1 = __expf(m1 - m);
  const float inv = 1.f / (l0 * e0 + l1 * e1);
  const int i = it * 64 + row;
  const size_t ob = ((size_t)(b * T_ + i)) * D_ + h * 64;
#pragma unroll
  for (int u = 0; u < 16; ++u) {
    int dd = dd0 + u;
    float v = (O0[row * 64 + dd] * e0 + O1[row * 64 + dd] * e1) * inv;
    ohi[ob + dd] = __float2bfloat16(v);
  }
}

// ======================= launch =======================
extern "C" void kernel_launch(void* const* d_in, const int* in_sizes, int n_in,
                              void* d_out, int out_size, void* d_ws, size_t ws_size,
                              hipStream_t stream) {
  (void)in_sizes; (void)n_in; (void)out_size; (void)ws_size;
  const float* x     = (const float*)d_in[0];
  const float* Wq    = (const float*)d_in[1];
  const float* Wk    = (const float*)d_in[2];
  const float* Wv    = (const float*)d_in[3];
  const float* Wo    = (const float*)d_in[4];
  const float* wA    = (const float*)d_in[5];
  const float* wB    = (const float*)d_in[6];
  const float* convw = (const float*)d_in[7];
  const float* bw    = (const float*)d_in[8];
  const float* gw    = (const float*)d_in[9];
  const float* gb    = (const float*)d_in[10];
  const float* qnw   = (const float*)d_in[11];
  const float* knw   = (const float*)d_in[12];

  const size_t N1 = (size_t)BT_ * D_;
  const size_t NTT = (size_t)BH_ * T_ * T_;
  float* ws = (float*)d_ws;
  float* wTb   = ws;                       // [BH,T,dh] fp32
  float* ypart = wTb + N1;                 // [4][BT][64] fp32
  float* beta  = ypart + (size_t)4 * BT_ * 64;
  float* G     = beta + (size_t)BH_ * T_;
  float* opart = G + (size_t)BH_ * T_;     // [BH*4*2][4096] fp32 = 4 MB
  float* mlbuf = opart + (size_t)BH_ * 4 * 2 * 4096;   // [BH*4*2][128]
  __hip_bfloat16* qb16  = (__hip_bfloat16*)(mlbuf + (size_t)BH_ * 4 * 2 * 128);
  __hip_bfloat16* kb16  = qb16 + N1;
  __hip_bfloat16* wb16  = kb16 + N1;
  __hip_bfloat16* abT   = wb16 + N1;            // [BH,T(j),T(t)] bf16
  __hip_bfloat16* linvb = abT + NTT;            // [BH,8,64,64] bf16
  __hip_bfloat16* xhi   = linvb + (size_t)BH_ * 8 * 4096;
  __hip_bfloat16* xlo   = xhi + N1;
  __hip_bfloat16* obhi  = xlo + N1;
  __hip_bfloat16* woThi = obhi + N1;
  __hip_bfloat16* vhi   = woThi + N1;           // [BH,dh,T] bf16
  __hip_bfloat16* wcThi = vhi + N1;             // [64][D]
  __hip_bfloat16* wcTlo = wcThi + (size_t)64 * D_;
  __hip_bfloat16* khat  = wcTlo + (size_t)64 * D_;  // [BH,8,T,dh] bf16
  __hip_bfloat16* wqkvT = khat + (size_t)BH_ * 8 * T_ * DH;  // [3072][D]

  prep_k<<<1600, 256, 0, stream>>>(x, Wq, Wk, Wv, Wo, wA, bw, gw,
                                   xhi, xlo, wqkvT, woThi, wcThi, wcTlo);
  gemm_qkv_ycat<<<dim3(52, 16), 256, 0, stream>>>(xhi, xlo, wqkvT, wcThi, wcTlo,
                                                  qb16, kb16, vhi, ypart, qnw, knw);
  gate_wdir<<<BT_ + BH_, 512, 0, stream>>>(ypart, gb, wB, convw, beta, G, wTb, wb16);
  linv_k<<<dim3(8, BH_), 256, 0, stream>>>(wTb, beta, linvb);
  chain_k<<<dim3(8, BH_), 256, 0, stream>>>(kb16, wb16, linvb, beta, abT, khat);
  attn_fused<<<dim3(12, BH_), 256, 0, stream>>>(qb16, wb16, khat, abT, vhi, G,
                                                obhi, opart, mlbuf);
  attn_merge<<<128, 256, 0, stream>>>(opart, mlbuf, obhi);
  gemm_o<<<dim3(16, 16), 256, 0, stream>>>(obhi, woThi, (float*)d_out);
}